// Round 5
// baseline (101.250 us; speedup 1.0000x reference)
//
#include <hip/hip_runtime.h>

// Problem constants (from reference)
#define N_CAM   6
#define N_HEADS 8
#define EMBD    256
#define HS      32
#define L       100     // seq_len = 10*10
#define BS      2
#define CAM_STRIDE (L * EMBD)   // 25600 floats per (b, cam)
#define CK      (N_CAM * L)     // 600 combined (cam, sk) index

// Workspace layout (floats):
//   wsum : 1536*256 = 393216   folded W (sum over 4 ref slots)
//   P    : 200*256*4 = 204800  split-K partials, float4 per (row,e): .c = chunk
//   E    : 200*8*100 = 160000  E[b*100+sq][h][sk] (camera-folded exp scores)
// (ktr slot removed R5: E reads feat directly — 128 contiguous B/lane, same
//  30 MB L2 volume, transpose round-trip deleted.)
#define WS_WSUM 0
#define WS_P    (WS_WSUM + 1536 * 256)
#define WS_E    (WS_P + 200 * 256 * 4)

// R3 post-mortem: cooperative grid.sync costs ~0.23us/block/sync on MI355X;
// fusion unviable. 3 stream-ordered launches; fixed harness floor ~75-84us
// (workspace poison fill 41.5us + launch/graph overhead) observed R2-R4.
// Controllable slice = kernels (+gaps) ~15-20us. This round: GEMM 8-row
// (L3 wsum traffic 78.6->39.3 MB), transpose deleted (E reads feat direct).

// ---------------------------------------------------------------------------
// L1 (384 blocks): fold W_v (1536x1024) over 4 ref slots -> wsum (1536x256).
// Pure stream: 6 MB read / 1.5 MB write.
// ---------------------------------------------------------------------------
__global__ __launch_bounds__(256) void prep_kernel(const float4* __restrict__ Wv4,
                                                   float* __restrict__ ws) {
    int tid = blockIdx.x * 256 + threadIdx.x;   // 384*256 = 1536 rows x 64 f4
    int i  = tid >> 6;
    int e4 = tid & 63;
    const float4* row = Wv4 + (size_t)i * 256;
    float4 a = row[e4];
    float4 b = row[64 + e4];
    float4 c = row[128 + e4];
    float4 d = row[192 + e4];
    float4 o;
    o.x = a.x + b.x + c.x + d.x;
    o.y = a.y + b.y + c.y + d.y;
    o.z = a.z + b.z + c.z + d.z;
    o.w = a.w + b.w + c.w + d.w;
    ((float4*)(ws + WS_WSUM))[(size_t)i * 64 + e4] = o;
}

// ---------------------------------------------------------------------------
// L2 (500 blocks) — GEMM partials + E-compute, co-scheduled for TLP:
//  blocks [0,100):  split-K GEMM, 8 rows/block: block=(rg,c), rows rg*8..+8,
//    K-chunk c of 384. Wave g owns kk-phase g: per iter one coalesced 1KB
//    float4 wsum read + 32 FMA. Phase-union LDS: a_tile (12KB) dies before
//    red4 (32KB) is born. wsum L3 traffic 39.3 MB (was 78.6). P layout
//    byte-identical float4/(row,e), .c = chunk.
//  blocks [100,500): E directly from feat: per lane 8 float4 = 128
//    contiguous bytes (2 full cachelines, no overfetch), L2-resident.
// ---------------------------------------------------------------------------
__global__ __launch_bounds__(256) void mid_kernel(const float* __restrict__ feat,
                                                  const float* __restrict__ query,
                                                  const float* __restrict__ ws_r,
                                                  float* __restrict__ ws_w) {
    __shared__ __align__(16) float4 smem4[2048];   // 32 KB phase-union
    const int t = threadIdx.x;

    if (blockIdx.x < 100) {
        // ---- GEMM: 8 rows x 384-K-chunk per block ----
        float* a_tile = (float*)smem4;           // 3072 floats (phase 1)
        const int rg = blockIdx.x >> 2;          // 0..24
        const int c  = blockIdx.x & 3;           // K-chunk
        const int r0 = rg * 8;                   // 0..192 (row 96..103 straddles
        const int k0 = c * 384;                  //  b; handled per-row below)

        for (int i = t; i < 8 * 384; i += 256) {
            int j  = i / 384;
            int kk = i - j * 384;
            int k  = k0 + kk;
            int cam = k >> 8, e2 = k & 255;
            int row = r0 + j;
            int b = row >= 100;
            int s = row - b * 100;
            a_tile[i] = feat[(size_t)(b * N_CAM + cam) * CAM_STRIDE + s * EMBD + e2];
        }
        __syncthreads();

        const int g  = t >> 6;      // wave id = kk phase (0..3)
        const int e4 = t & 63;      // owns e = 4*e4 .. 4*e4+3
        float4 acc[8];
#pragma unroll
        for (int j = 0; j < 8; ++j) acc[j] = make_float4(0.f, 0.f, 0.f, 0.f);

        // wsum4[(k0+kk)*64 + e4], kk = 4*kk2 + g
        const float4* wp4 = (const float4*)(ws_r + WS_WSUM)
                          + (size_t)(k0 + g) * 64 + e4;
#pragma unroll 8
        for (int kk2 = 0; kk2 < 96; ++kk2) {
            float4 w = wp4[(size_t)kk2 * 256];   // 1KB/wave coalesced
            int kk = kk2 * 4 + g;
#pragma unroll
            for (int j = 0; j < 8; ++j) {
                float a = a_tile[j * 384 + kk];  // wave-uniform LDS broadcast
                acc[j].x += a * w.x;
                acc[j].y += a * w.y;
                acc[j].z += a * w.z;
                acc[j].w += a * w.w;
            }
        }
        __syncthreads();                         // a_tile dead; reuse as red4

        float4* red4 = smem4;                    // [g][row8][e4] = 2048 f4
#pragma unroll
        for (int j = 0; j < 8; ++j)
            red4[(g * 8 + j) * 64 + e4] = acc[j];
        __syncthreads();

        // 512 (row,e4) sums over 256 threads: 2 each
        float* P = ws_w + WS_P;
        for (int q = t; q < 512; q += 256) {
            int row = q >> 6;                    // 0..7
            int ee  = q & 63;
            float4 s0 = red4[(0 * 8 + row) * 64 + ee];
            float4 s1 = red4[(1 * 8 + row) * 64 + ee];
            float4 s2 = red4[(2 * 8 + row) * 64 + ee];
            float4 s3 = red4[(3 * 8 + row) * 64 + ee];
            float4 s;
            s.x = s0.x + s1.x + s2.x + s3.x;
            s.y = s0.y + s1.y + s2.y + s3.y;
            s.z = s0.z + s1.z + s2.z + s3.z;
            s.w = s0.w + s1.w + s2.w + s3.w;
            size_t base = ((size_t)(r0 + row) * 256 + ee * 4) * 4 + c;
            P[base + 0 * 4] = s.x;
            P[base + 1 * 4] = s.y;
            P[base + 2 * 4] = s.z;
            P[base + 3 * 4] = s.w;
        }
    } else {
        // ---- E branch: block = (b, h, sq-tile of 4), reads feat direct ----
        float* q_s = (float*)smem4;        // 128 floats
        float* es  = (float*)smem4 + 128;  // 2400 floats: exp(scores) 4sq x 600ck
        int idx = blockIdx.x - 100;        // [0,400)
        int b   = idx / 200;
        int rem = idx - b * 200;
        int h   = rem / 25;
        int sqt = rem - h * 25;
        int sq0 = sqt * 4;

        if (t < 128)
            q_s[t] = query[(size_t)(b * L + sq0 + (t >> 5)) * EMBD + h * HS + (t & 31)];
        __syncthreads();

        const float scale = 0.17677669529663687f;  // 1/sqrt(32)
        const float4* f4 = reinterpret_cast<const float4*>(feat);

#pragma unroll
        for (int i = 0; i < 3; ++i) {
            int ck = t + i * 256;
            if (ck < CK) {
                int cam = ck / 100;
                int sk  = ck - cam * 100;
                // feat[b,cam, sk*256 + h*32 + d4*4 ..]: 128 contiguous B/lane
                const float4* kp = f4 + (size_t)(b * N_CAM + cam) * (CAM_STRIDE / 4)
                                 + sk * 64 + h * 8;
                float acc0 = 0.f, acc1 = 0.f, acc2 = 0.f, acc3 = 0.f;
#pragma unroll
                for (int d4 = 0; d4 < 8; ++d4) {
                    float4 kv = kp[d4];
                    const float* q0 = &q_s[0 * 32 + d4 * 4];
                    const float* q1 = &q_s[1 * 32 + d4 * 4];
                    const float* q2 = &q_s[2 * 32 + d4 * 4];
                    const float* q3 = &q_s[3 * 32 + d4 * 4];
                    acc0 += q0[0] * kv.x + q0[1] * kv.y + q0[2] * kv.z + q0[3] * kv.w;
                    acc1 += q1[0] * kv.x + q1[1] * kv.y + q1[2] * kv.z + q1[3] * kv.w;
                    acc2 += q2[0] * kv.x + q2[1] * kv.y + q2[2] * kv.z + q2[3] * kv.w;
                    acc3 += q3[0] * kv.x + q3[1] * kv.y + q3[2] * kv.z + q3[3] * kv.w;
                }
                es[0 * CK + ck] = __expf(acc0 * scale);
                es[1 * CK + ck] = __expf(acc1 * scale);
                es[2 * CK + ck] = __expf(acc2 * scale);
                es[3 * CK + ck] = __expf(acc3 * scale);
            }
        }
        __syncthreads();

        // camera fold -> E
        float* E = ws_w + WS_E;
        for (int p = t; p < 4 * L; p += 256) {
            int sj = p / 100, sk = p - sj * 100;
            float e = 0.f;
#pragma unroll
            for (int cam = 0; cam < N_CAM; ++cam)
                e += es[sj * CK + cam * L + sk];
            E[((size_t)(b * L + sq0 + sj) * N_HEADS + h) * L + sk] = e;
        }
    }
}

// ---------------------------------------------------------------------------
// L3 (100 blocks): block = (b, sq-pair). P[b] slab amortized over 2 queries.
// out[b,sq,e] = (sum_sk E*(p.x+p.y+p.z+p.w) + sumE*bias_e) * 0.25/sumE
// ---------------------------------------------------------------------------
__global__ __launch_bounds__(256) void out_kernel(const float* __restrict__ ws,
                                                  const float* __restrict__ b_v,
                                                  float* __restrict__ out) {
    __shared__ float E_s[2 * N_HEADS * L];    // 1600 floats, 2 queries
    const int t   = threadIdx.x;
    const int b   = blockIdx.x / 50;
    const int sq0 = (blockIdx.x - b * 50) * 2;

    const float* E = ws + WS_E + (size_t)(b * L + sq0) * N_HEADS * L;
    for (int i = t; i < 2 * N_HEADS * L; i += 256) E_s[i] = E[i];
    __syncthreads();

    const int h = t >> 5;
    float sumE0 = 0.f, sumE1 = 0.f;
#pragma unroll 4
    for (int sk = 0; sk < L; ++sk) {
        sumE0 += E_s[h * L + sk];                 // broadcast reads (free)
        sumE1 += E_s[N_HEADS * L + h * L + sk];
    }

    float bias = b_v[t] + b_v[256 + t] + b_v[512 + t] + b_v[768 + t];

    const float4* p4 = (const float4*)(ws + WS_P) + (size_t)b * L * 256 + t;
    float acc0 = 0.f, acc1 = 0.f;
#pragma unroll 16
    for (int sk = 0; sk < L; ++sk) {
        float4 p = p4[(size_t)sk * 256];  // 16B coalesced, folds 4 K-chunks
        float s = p.x + p.y + p.z + p.w;
        acc0 += E_s[h * L + sk] * s;
        acc1 += E_s[N_HEADS * L + h * L + sk] * s;
    }

    out[(size_t)(b * L + sq0 + 0) * EMBD + t] = (acc0 + sumE0 * bias) * (0.25f / sumE0);
    out[(size_t)(b * L + sq0 + 1) * EMBD + t] = (acc1 + sumE1 * bias) * (0.25f / sumE1);
}

// ---------------------------------------------------------------------------
extern "C" void kernel_launch(void* const* d_in, const int* in_sizes, int n_in,
                              void* d_out, int out_size, void* d_ws, size_t ws_size,
                              hipStream_t stream) {
    const float* feat  = (const float*)d_in[0];  // (2,1,6,256,10,10)
    const float* query = (const float*)d_in[1];  // (2,100,256)
    const float4* Wv   = (const float4*)d_in[2]; // (1536,1024)
    const float* bv    = (const float*)d_in[3];  // (1024,)
    float* outp = (float*)d_out;                 // (2,100,256)
    float* ws   = (float*)d_ws;

    // L1: W fold only (transpose deleted — E reads feat directly)
    prep_kernel<<<384, 256, 0, stream>>>(Wv, ws);
    // L2: split-K GEMM (100 blk, 8-row float4) + E-compute (400 blk)
    mid_kernel<<<500, 256, 0, stream>>>(feat, query, ws, ws);
    // L3: E-weighted reduce + bias + normalize, 2 sq per block
    out_kernel<<<100, 256, 0, stream>>>(ws, bv, outp);
}

// Round 6
// 88.727 us; speedup vs baseline: 1.1411x; 1.1411x over previous
//
#include <hip/hip_runtime.h>

// Problem constants (from reference)
#define N_CAM   6
#define N_HEADS 8
#define EMBD    256
#define HS      32
#define L       100     // seq_len = 10*10
#define BS      2
#define CAM_STRIDE (L * EMBD)   // 25600 floats per (b, cam)
#define CK      (N_CAM * L)     // 600 combined (cam, sk) index

// Workspace layout (floats) — identical to the 90.4us session-best:
//   wsum : 1536*256 = 393216   folded W (sum over 4 ref slots)  [L2-resident]
//   ktr  : 2*8*8*600 float4 = 307200 floats  [b][h][d4][ck] float4-packed K
//   P    : 200*256*4 = 204800  split-K partials, float4 per (row,e): .c = chunk
//   E    : 200*8*100 = 160000  E[b*100+sq][h][sk] (camera-folded exp scores)
#define WS_WSUM 0
#define WS_KTR  (WS_WSUM + 1536 * 256)
#define WS_P    (WS_KTR + 2 * N_HEADS * 8 * CK * 4)
#define WS_E    (WS_P + 200 * 256 * 4)

// R0-R5 lessons (measured):
//  - Latency/TLP-bound regime: every block-count reduction hurt ~+4us per
//    halving, even when it halved L2 traffic. Keep 400 GEMM / 400 E / 200 out.
//  - E must read the ktr transpose (16B/lane coalesced); feat-direct gathers
//    64 cachelines/instruction and regressed (R5).
//  - Cooperative grid.sync ~0.23us/block/sync -> fusion unviable (R2/R3).
//  - float4-wave GEMM inner loop helped +4.3us at constant shape (R1->R4);
//    this round applies it at the proven 400-block/2-row shape.

// ---------------------------------------------------------------------------
// L1 (480 blocks) — independent prep jobs (session-best, unchanged):
//  blocks [0,96):  transpose feat -> ktr4[b][h][d4][cam*100+sk] (float4 over d)
//  blocks [96,480): fold W_v (1536x1024) over 4 ref slots -> wsum (1536x256)
// ---------------------------------------------------------------------------
__global__ __launch_bounds__(256) void prep_kernel(const float* __restrict__ feat,
                                                   const float4* __restrict__ Wv4,
                                                   float* __restrict__ ws) {
    const int t = threadIdx.x;
    if (blockIdx.x < 96) {
        __shared__ float tile[100 * 33];  // +1 pad: conflict-free column reads
        int blk = blockIdx.x;
        int b   = blk / 48;
        int rem = blk - b * 48;
        int cam = rem >> 3;
        int h   = rem & 7;
        const float4* src4 = reinterpret_cast<const float4*>(
            feat + (size_t)(b * N_CAM + cam) * CAM_STRIDE + h * HS);
        for (int idx = t; idx < 100 * 8; idx += 256) {
            int sk = idx >> 3;
            int d4 = idx & 7;
            float4 v = src4[sk * (EMBD / 4) + d4];       // 128B-contiguous runs
            float* dst = &tile[sk * 33 + d4 * 4];
            dst[0] = v.x; dst[1] = v.y; dst[2] = v.z; dst[3] = v.w;
        }
        __syncthreads();
        float4* ktr4 = reinterpret_cast<float4*>(ws + WS_KTR)
                     + (size_t)(b * N_HEADS + h) * 8 * CK + cam * L;
        for (int idx = t; idx < 8 * 100; idx += 256) {
            int d4 = idx / 100;
            int sk = idx - d4 * 100;
            const float* s = &tile[sk * 33 + d4 * 4];    // banks cycle (33%32==1)
            ktr4[(size_t)d4 * CK + sk] = make_float4(s[0], s[1], s[2], s[3]);
        }
    } else {
        // wsum[i][e] = sum_ref W_v[i][ref*256+e]
        int tid = (blockIdx.x - 96) * 256 + t;
        int i  = tid >> 6;
        int e4 = tid & 63;
        const float4* row = Wv4 + (size_t)i * 256;
        float4 a = row[e4];
        float4 b = row[64 + e4];
        float4 c = row[128 + e4];
        float4 d = row[192 + e4];
        float4 o;
        o.x = a.x + b.x + c.x + d.x;
        o.y = a.y + b.y + c.y + d.y;
        o.z = a.z + b.z + c.z + d.z;
        o.w = a.w + b.w + c.w + d.w;
        ((float4*)(ws + WS_WSUM))[(size_t)i * 64 + e4] = o;
    }
}

// ---------------------------------------------------------------------------
// L2 (800 blocks) — GEMM partials + E-compute, co-scheduled for TLP:
//  blocks [0,400):  split-K GEMM at proven 2-row/400-block shape, with the
//    float4-wave inner loop: wave g owns kk phase g; per iter one coalesced
//    1KB float4 wsum load + 8 FMA (96 iters, was 384 scalar-load iters).
//    8KB LDS cross-wave reduce; P layout byte-identical float4/(row,e).
//  blocks [400,800): E from float4-packed ktr (session-best, unchanged).
// ---------------------------------------------------------------------------
__global__ __launch_bounds__(256) void mid_kernel(const float* __restrict__ feat,
                                                  const float* __restrict__ query,
                                                  const float* __restrict__ ws_r,
                                                  float* __restrict__ ws_w) {
    __shared__ __align__(16) float smem[2528];   // union: a_tile 768 | red4 2048 | q_s+es 2528
    const int t = threadIdx.x;
    if (blockIdx.x < 400) {
        // ---- GEMM branch: 2 rows x 384-K-chunk, float4-wave inner loop ----
        float* a_tile = smem;                    // 768 floats (phase 1)
        const int rg = blockIdx.x >> 2;          // 0..99
        const int c  = blockIdx.x & 3;           // K-chunk
        const int r0 = rg * 2;
        const int k0 = c * 384;

        for (int i = t; i < 768; i += 256) {
            int j  = i >= 384;
            int kk = i - j * 384;
            int k  = k0 + kk;
            int cam = k >> 8, e2 = k & 255;
            int row = r0 + j;
            int b = row >= 100;
            int s = row - b * 100;
            a_tile[i] = feat[(size_t)(b * N_CAM + cam) * CAM_STRIDE + s * EMBD + e2];
        }
        __syncthreads();

        const int g  = t >> 6;      // wave id = kk phase (0..3)
        const int e4 = t & 63;      // owns e = 4*e4 .. 4*e4+3
        float4 acc0 = {0.f, 0.f, 0.f, 0.f}, acc1 = acc0;
        // wsum4[(k0+kk)*64 + e4], kk = 4*kk2 + g
        const float4* wp4 = (const float4*)(ws_r + WS_WSUM)
                          + (size_t)(k0 + g) * 64 + e4;
#pragma unroll 8
        for (int kk2 = 0; kk2 < 96; ++kk2) {
            float4 w = wp4[(size_t)kk2 * 256];   // 1KB/wave coalesced, L2-hit
            int kk = kk2 * 4 + g;
            float a0 = a_tile[kk];               // wave-uniform LDS broadcast
            float a1 = a_tile[384 + kk];
            acc0.x += a0 * w.x; acc0.y += a0 * w.y; acc0.z += a0 * w.z; acc0.w += a0 * w.w;
            acc1.x += a1 * w.x; acc1.y += a1 * w.y; acc1.z += a1 * w.z; acc1.w += a1 * w.w;
        }
        __syncthreads();                         // a_tile dead; reuse as red4

        float4* red4 = (float4*)smem;            // [g][row2][e4] = 512 f4, 8KB
        red4[(g * 2 + 0) * 64 + e4] = acc0;
        red4[(g * 2 + 1) * 64 + e4] = acc1;
        __syncthreads();

        if (t < 128) {                           // 2 rows x 64 e4
            int row = t >> 6, ee = t & 63;
            float4 s0 = red4[(0 * 2 + row) * 64 + ee];
            float4 s1 = red4[(1 * 2 + row) * 64 + ee];
            float4 s2 = red4[(2 * 2 + row) * 64 + ee];
            float4 s3 = red4[(3 * 2 + row) * 64 + ee];
            float4 s;
            s.x = s0.x + s1.x + s2.x + s3.x;
            s.y = s0.y + s1.y + s2.y + s3.y;
            s.z = s0.z + s1.z + s2.z + s3.z;
            s.w = s0.w + s1.w + s2.w + s3.w;
            float* P = ws_w + WS_P;
            size_t base = ((size_t)(r0 + row) * 256 + ee * 4) * 4 + c;
            P[base + 0 * 4] = s.x;
            P[base + 1 * 4] = s.y;
            P[base + 2 * 4] = s.z;
            P[base + 3 * 4] = s.w;
        }
    } else {
        // ---- E branch: block = (b, h, sq-tile of 4) ----
        float* q_s = smem;         // 128 floats
        float* es  = smem + 128;   // 2400 floats: exp(scores) 4 sq x 600 ck
        int idx = blockIdx.x - 400;       // [0,400)
        int b   = idx / 200;
        int rem = idx - b * 200;
        int h   = rem / 25;
        int sqt = rem - h * 25;
        int sq0 = sqt * 4;

        if (t < 128)
            q_s[t] = query[(size_t)(b * L + sq0 + (t >> 5)) * EMBD + h * HS + (t & 31)];
        __syncthreads();

        const float scale = 0.17677669529663687f;  // 1/sqrt(32)
        const float4* kt4 = reinterpret_cast<const float4*>(ws_r + WS_KTR)
                          + (size_t)(b * N_HEADS + h) * 8 * CK;

#pragma unroll
        for (int i = 0; i < 3; ++i) {
            int ck = t + i * 256;
            if (ck < CK) {
                float acc0 = 0.f, acc1 = 0.f, acc2 = 0.f, acc3 = 0.f;
#pragma unroll
                for (int d4 = 0; d4 < 8; ++d4) {
                    float4 kv = kt4[(size_t)d4 * CK + ck];   // 16B/lane coalesced
                    const float* q0 = &q_s[0 * 32 + d4 * 4];
                    const float* q1 = &q_s[1 * 32 + d4 * 4];
                    const float* q2 = &q_s[2 * 32 + d4 * 4];
                    const float* q3 = &q_s[3 * 32 + d4 * 4];
                    acc0 += q0[0] * kv.x + q0[1] * kv.y + q0[2] * kv.z + q0[3] * kv.w;
                    acc1 += q1[0] * kv.x + q1[1] * kv.y + q1[2] * kv.z + q1[3] * kv.w;
                    acc2 += q2[0] * kv.x + q2[1] * kv.y + q2[2] * kv.z + q2[3] * kv.w;
                    acc3 += q3[0] * kv.x + q3[1] * kv.y + q3[2] * kv.z + q3[3] * kv.w;
                }
                es[0 * CK + ck] = __expf(acc0 * scale);
                es[1 * CK + ck] = __expf(acc1 * scale);
                es[2 * CK + ck] = __expf(acc2 * scale);
                es[3 * CK + ck] = __expf(acc3 * scale);
            }
        }
        __syncthreads();

        // camera fold -> E
        float* E = ws_w + WS_E;
        for (int p = t; p < 4 * L; p += 256) {
            int sj = p / 100, sk = p - sj * 100;
            float e = 0.f;
#pragma unroll
            for (int cam = 0; cam < N_CAM; ++cam)
                e += es[sj * CK + cam * L + sk];
            E[((size_t)(b * L + sq0 + sj) * N_HEADS + h) * L + sk] = e;
        }
    }
}

// ---------------------------------------------------------------------------
// L3 (200 blocks): block = (b, sq) — session-best shape (more blocks > less
// traffic in this latency-bound regime).
// out[b,sq,e] = (sum_sk E*(p.x+p.y+p.z+p.w) + sumE*bias_e) * 0.25/sumE
// ---------------------------------------------------------------------------
__global__ __launch_bounds__(256) void out_kernel(const float* __restrict__ ws,
                                                  const float* __restrict__ b_v,
                                                  float* __restrict__ out) {
    __shared__ float E_s[N_HEADS * L];    // 800 floats
    const int t  = threadIdx.x;
    const int b  = blockIdx.x / 100;
    const int sq = blockIdx.x - b * 100;

    const float* E = ws + WS_E + (size_t)(b * L + sq) * N_HEADS * L;
    for (int i = t; i < N_HEADS * L; i += 256) E_s[i] = E[i];
    __syncthreads();

    const int h = t >> 5;
    float sumE = 0.f;
#pragma unroll 4
    for (int sk = 0; sk < L; ++sk) sumE += E_s[h * L + sk];   // broadcast reads

    float bias = b_v[t] + b_v[256 + t] + b_v[512 + t] + b_v[768 + t];

    const float4* p4 = (const float4*)(ws + WS_P) + (size_t)b * L * 256 + t;
    float acc = 0.f;
#pragma unroll 16
    for (int sk = 0; sk < L; ++sk) {
        float4 p = p4[(size_t)sk * 256];  // 16B coalesced, folds 4 K-chunks
        acc += E_s[h * L + sk] * (p.x + p.y + p.z + p.w);
    }

    out[(size_t)(b * L + sq) * EMBD + t] = (acc + sumE * bias) * (0.25f / sumE);
}

// ---------------------------------------------------------------------------
extern "C" void kernel_launch(void* const* d_in, const int* in_sizes, int n_in,
                              void* d_out, int out_size, void* d_ws, size_t ws_size,
                              hipStream_t stream) {
    const float* feat  = (const float*)d_in[0];  // (2,1,6,256,10,10)
    const float* query = (const float*)d_in[1];  // (2,100,256)
    const float4* Wv   = (const float4*)d_in[2]; // (1536,1024)
    const float* bv    = (const float*)d_in[3];  // (1024,)
    float* outp = (float*)d_out;                 // (2,100,256)
    float* ws   = (float*)d_ws;

    // L1: float4-packed ktr transpose + W fold (independent, one launch)
    prep_kernel<<<480, 256, 0, stream>>>(feat, Wv, ws);
    // L2: split-K GEMM (400 blk, 2-row float4-wave) + E-compute (400 blk)
    mid_kernel<<<800, 256, 0, stream>>>(feat, query, ws, ws);
    // L3: E-weighted reduce + bias + normalize, 1 sq per block
    out_kernel<<<200, 256, 0, stream>>>(ws, bv, outp);
}